// Round 8
// baseline (142.073 us; speedup 1.0000x reference)
//
#include <hip/hip_runtime.h>
#include <math.h>

// ---------------- problem constants ----------------
#define NROWS  23328           // 8 * 54 * 54
#define SPAT   2916            // 54*54
#define HIN    56
#define IMG    3136            // 56*56
#define CIMG   200704          // 64*3136
#define NOUT   2985984         // 23328*128
#define NRB    365             // 64-row blocks (last has 32 valid rows)
#define NCHT   9               // chunks per K-third
#define CH     6               // k32-steps per chunk (24 g-slots)

// ---------------- ws layout (bytes) ----------------
#define W2_OFF    0u                         // [648][128][8] bf16 = 1327104
#define ACT8_OFF  1335296u                   // [NPIX][8] bf16 = 25690112
#define SILU_OFF  27025408u                  // [NHW][64] bf16 = 3211264
#define PART_OFF  30236672u                  // [2][NOUT] f32 = 23887872
#define WS_NEED   (PART_OFF + 2u * NOUT * 4u)   // 54.1 MB (proven available)

// prep idx ranges
#define R_SIL_END  200704
#define R_W2_END   864256                    // +663552
#define R_ACT_END  1265664                   // +401408

typedef __bf16 bf16x8 __attribute__((ext_vector_type(8)));
typedef float  floatx4 __attribute__((ext_vector_type(4)));

#define GL2LDS(SRC, DST) __builtin_amdgcn_global_load_lds( \
    (const __attribute__((address_space(1))) unsigned int*)(SRC), \
    (__attribute__((address_space(3))) unsigned int*)(DST), 16, 0, 0)

__device__ __forceinline__ float silu_f(float p) {
    return p / (1.f + __expf(-p));
}

__device__ __forceinline__ bf16x8 bases8(float p) {
    float u  = p * 2.5f + 5.5f;              // uniform grid [-2.2,2.2], h=0.4
    float fk = floorf(u);
    int   kk = (int)fk;
    float t  = u - fk;
    float t2 = t * t, t3 = t2 * t;
    float omt = 1.f - t;
    float w0 = omt * omt * omt * (1.f / 6.f);
    float w1 = (3.f * t3 - 6.f * t2 + 4.f) * (1.f / 6.f);
    float w2 = (-3.f * t3 + 3.f * t2 + 3.f * t + 1.f) * (1.f / 6.f);
    float w3 = t3 * (1.f / 6.f);
    bool inr = (u >= 0.f) && (u < 11.f);
    bf16x8 v;
#pragma unroll
    for (int g = 0; g < 8; ++g) {
        int d = kk - g;
        float val = (d == 3) ? w0 : (d == 2) ? w1
                  : (d == 1) ? w2 : (d == 0) ? w3 : 0.f;
        v[g] = (__bf16)(inr ? val : 0.f);
    }
    return v;
}

// ---------------------------------------------------------------------------
// Prep: silu transpose, W2 planes ([g][cout][8], g = k/8), act8 planes.
// ---------------------------------------------------------------------------
__global__ __launch_bounds__(256) void prep_kernel(
    const float* __restrict__ x, const float* __restrict__ bw,
    const float* __restrict__ sw, const float* __restrict__ sc,
    char* __restrict__ ws)
{
    __bf16* W2    = (__bf16*)(ws + W2_OFF);
    __bf16* act8  = (__bf16*)(ws + ACT8_OFF);
    __bf16* silu_t= (__bf16*)(ws + SILU_OFF);

    int idx = blockIdx.x * 256 + threadIdx.x;
    if (idx < R_SIL_END) {
        int c8 = idx & 7;
        int r  = idx >> 3;                   // b*IMG + hw
        int b  = r / IMG;
        int hw = r - b * IMG;
        const float* xb = x + b * CIMG + (c8 * 8) * IMG + hw;
        bf16x8 v;
#pragma unroll
        for (int j = 0; j < 8; ++j) v[j] = (__bf16)silu_f(xb[j * IMG]);
        *(bf16x8*)(silu_t + (size_t)r * 64 + c8 * 8) = v;
    } else if (idx < R_W2_END) {
        int iw = idx - R_SIL_END;
        int j  = iw & 7;
        int o  = (iw >> 3) & 127;
        int g  = iw >> 10;                   // 0..647
        float val;
        if (g < 576) {
            val = sw[(o * 576 + g) * 8 + j] * sc[o * 576 + g];
        } else {
            int eb = g - 576;
            int rs = eb >> 3;
            int c  = (eb & 7) * 8 + j;
            val = bw[o * 576 + c * 9 + rs];
        }
        W2[iw] = (__bf16)val;
    } else if (idx < R_ACT_END) {
        int i4 = idx - R_W2_END;
        float4 p = ((const float4*)x)[i4];
        __bf16* dst = act8 + (size_t)i4 * 32;
        *(bf16x8*)(dst)      = bases8(p.x);
        *(bf16x8*)(dst + 8)  = bases8(p.y);
        *(bf16x8*)(dst + 16) = bases8(p.z);
        *(bf16x8*)(dst + 24) = bases8(p.w);
    }
}

// ---------------------------------------------------------------------------
// GEMM: 1095 blocks = 365 row-blocks x 3 K-thirds, 256 threads (4 waves).
// Block = 64 rows x 128 couts x third-K; wave = 64 rows x 32 couts (4x2 acc)
// -> each W fragment feeds 4 MFMAs (halves W L2 traffic vs R7).
// A staged by async global_load_lds, double-buffered, 6 K32-steps per chunk
// (half the barriers of R7); W register-pipelined one k-step ahead.
// MODE 0: thirds 0,1 -> fp32 partials; third 2 -> direct store to out;
// reduce does out += p0 + p1. MODE 1: atomicAdd fallback.
// ---------------------------------------------------------------------------
template <int MODE>
__global__ __launch_bounds__(256, 3) void kan_gemm(
    char* __restrict__ ws, float* __restrict__ outp)
{
    const __bf16* W2     = (const __bf16*)(ws + W2_OFF);
    const __bf16* act8   = (const __bf16*)(ws + ACT8_OFF);
    const __bf16* silu_t = (const __bf16*)(ws + SILU_OFF);
    float*        part   = (float*)(ws + PART_OFF);

    __shared__ __align__(16) char As[2][24 * 1024];   // 49,152 B

    const int tid   = threadIdx.x;
    const int lane  = tid & 63;
    const int wave  = tid >> 6;          // 0..3 = cout group of 32
    const int quad  = lane >> 4;
    const int l16   = lane & 15;
    const int third = blockIdx.x % 3;    // K-third
    const int rb    = blockIdx.x / 3;
    const int n0    = rb * 64;

    // staging identity: lane = local row (64 rows = 64 lanes), clamped
    const int nrow = n0 + lane;
    const int ncl  = nrow < NROWS ? nrow : NROWS - 1;
    const int bb   = ncl / SPAT;
    const int rr   = ncl - bb * SPAT;
    const int ohh  = rr / 54, oww = rr - (rr / 54) * 54;
    const size_t pb = (size_t)bb * CIMG + ohh * HIN + oww;    // pixel index
    const size_t sb = ((size_t)bb * IMG + ohh * HIN + oww) * 64;

    floatx4 acc[4][2] = {};
    const int gbase0 = third * 216;      // g = k/8 index base for this third

    auto stage = [&](int chunk, int buf) {
        int gbase = gbase0 + chunk * 24;
#pragma unroll
        for (int j = 0; j < 6; ++j) {
            int gl = wave * 6 + j;           // LDS slot 0..23 (wave-uniform)
            int g  = gbase + gl;             // global k/8 index 0..647
            const char* src;
            if (g < 576) {                   // spline planes
                int c  = g / 9;
                int rs = g - 9 * c;
                int rw = rs / 3;
                int off = c * IMG + rw * HIN + (rs - rw * 3);
                src = (const char*)(act8 + (pb + off) * 8);
            } else {                         // base/silu planes
                int eb = g - 576;
                int rs = eb >> 3;
                int rw = rs / 3;
                int off = (rw * HIN + (rs - rw * 3)) * 64 + (eb & 7) * 8;
                src = (const char*)(silu_t + sb + off);
            }
            GL2LDS(src, &As[buf][gl * 1024]);
        }
    };

    stage(0, 0);
    __syncthreads();

    for (int i = 0; i < NCHT; ++i) {
        const int buf = i & 1;
        if (i + 1 < NCHT) stage(i + 1, buf ^ 1);   // async prefetch

        const int gq0 = gbase0 + i * 24 + quad;
        bf16x8 wcur[2], wnext[2];
#pragma unroll
        for (int nt = 0; nt < 2; ++nt)
            wcur[nt] = *(const bf16x8*)(W2 +
                ((size_t)gq0 * 128 + wave * 32 + nt * 16 + l16) * 8);
#pragma unroll
        for (int ks = 0; ks < CH; ++ks) {
            if (ks + 1 < CH) {
                int gq = gq0 + (ks + 1) * 4;
#pragma unroll
                for (int nt = 0; nt < 2; ++nt)
                    wnext[nt] = *(const bf16x8*)(W2 +
                        ((size_t)gq * 128 + wave * 32 + nt * 16 + l16) * 8);
            }
            bf16x8 afr[4];
#pragma unroll
            for (int mt = 0; mt < 4; ++mt)
                afr[mt] = *(const bf16x8*)(&As[buf][
                    ((ks * 4 + quad) * 64 + mt * 16 + l16) * 16]);
#pragma unroll
            for (int mt = 0; mt < 4; ++mt)
#pragma unroll
                for (int nt = 0; nt < 2; ++nt)
                    acc[mt][nt] = __builtin_amdgcn_mfma_f32_16x16x32_bf16(
                        wcur[nt], afr[mt], acc[mt][nt], 0, 0, 0);
            if (ks + 1 < CH) { wcur[0] = wnext[0]; wcur[1] = wnext[1]; }
        }
        __syncthreads();
    }

    // epilogue: D col(l16) = row n, D row(quad*4+r) = cout -> coalesced
#pragma unroll
    for (int mt = 0; mt < 4; ++mt) {
        int nn = n0 + mt * 16 + l16;
        if (nn < NROWS) {
            int b2   = nn / SPAT;
            int rem2 = nn - b2 * SPAT;
#pragma unroll
            for (int nt = 0; nt < 2; ++nt) {
#pragma unroll
                for (int r = 0; r < 4; ++r) {
                    int o = wave * 32 + nt * 16 + quad * 4 + r;
                    size_t idx = (size_t)(b2 * 128 + o) * SPAT + rem2;
                    float v = acc[mt][nt][r];
                    if (MODE == 0) {
                        if (third < 2) part[(size_t)third * NOUT + idx] = v;
                        else           outp[idx] = v;
                    } else {
                        atomicAdd(&outp[idx], v);
                    }
                }
            }
        }
    }
}

__global__ __launch_bounds__(256) void reduce_kernel(
    const char* __restrict__ ws, float* __restrict__ outp)
{
    const floatx4* p0 = (const floatx4*)(ws + PART_OFF);
    const floatx4* p1 = p0 + NOUT / 4;
    int i = blockIdx.x * 256 + threadIdx.x;   // grid covers NOUT/4 exactly
    floatx4 a = p0[i], b = p1[i], c = ((const floatx4*)outp)[i];
    ((floatx4*)outp)[i] = (floatx4){a[0] + b[0] + c[0], a[1] + b[1] + c[1],
                                    a[2] + b[2] + c[2], a[3] + b[3] + c[3]};
}

__global__ __launch_bounds__(256) void zero_kernel(float* __restrict__ outp)
{
    int i = blockIdx.x * 256 + threadIdx.x;
    ((floatx4*)outp)[i] = (floatx4){0.f, 0.f, 0.f, 0.f};
}

extern "C" void kernel_launch(void* const* d_in, const int* in_sizes, int n_in,
                              void* d_out, int out_size, void* d_ws, size_t ws_size,
                              hipStream_t stream) {
    const float* x  = (const float*)d_in[0];
    const float* bw = (const float*)d_in[1];
    const float* sw = (const float*)d_in[2];
    const float* sc = (const float*)d_in[3];
    float* out = (float*)d_out;
    char*  ws  = (char*)d_ws;

    prep_kernel<<<R_ACT_END / 256, 256, 0, stream>>>(x, bw, sw, sc, ws);

    if (ws_size >= WS_NEED) {
        kan_gemm<0><<<NRB * 3, 256, 0, stream>>>(ws, out);
        reduce_kernel<<<NOUT / 4 / 256, 256, 0, stream>>>(ws, out);
    } else {
        zero_kernel<<<NOUT / 4 / 256, 256, 0, stream>>>(out);
        kan_gemm<1><<<NRB * 3, 256, 0, stream>>>(ws, out);
    }
}